// Round 2
// baseline (432.397 us; speedup 1.0000x reference)
//
#include <hip/hip_runtime.h>

// EMA with bias correction along last axis.
// x: (32, 256, 8192) fp32  ->  out same shape.
// y[t] = 0.99*y[t-1] + 0.01*x[t], y[-1]=0 ; out[t] = y[t] / (1 - 0.99^(t+1))
//
// One 256-thread block per row (8192 rows). Chunked scan, v2:
//   - LDS laid out as float4 units with 16B-granularity XOR swizzle
//     (u ^ ((u>>3)&7)): ds_{read,write}_b128 conflict-free in ALL phases
//     (stage-in coalesced writes, per-thread chunk reads/writes, stage-out
//     coalesced reads). 32 b128 LDS ops/thread vs 128 scalar in v1.
//   - per-thread 32-elem sequential scan in registers,
//   - Kogge-Stone shuffle carry scan with constexpr decay powers,
//   - epilogue uses constexpr power tables (no serial multiply chains).

namespace {

constexpr int T = 8192;
constexpr int BLOCK = 256;
constexpr int CHUNK = T / BLOCK;       // 32 elements per thread
constexpr int NWAVE = BLOCK / 64;      // 4
constexpr int UNITS = T / 4;           // 2048 float4 units per row
constexpr int VECS = UNITS / BLOCK;    // 8 float4 per thread

__device__ __forceinline__ int swu(int u) { return u ^ ((u >> 3) & 7); }

constexpr float powc(int n) {
  float r = 1.0f;
  for (int i = 0; i < n; ++i) r *= 0.99f;
  return r;
}

struct Pows { float p[CHUNK + 1]; };
constexpr Pows make_pows() {
  Pows q{};
  float r = 1.0f;
  q.p[0] = 1.0f;
  for (int i = 1; i <= CHUNK; ++i) { r *= 0.99f; q.p[i] = r; }
  return q;
}
constexpr Pows PW = make_pows();

constexpr float A1 = 0.99f, M = 0.01f;
constexpr float A32 = powc(32);     // decay across one chunk
constexpr float A64 = powc(64);
constexpr float A128 = powc(128);
constexpr float A256 = powc(256);
constexpr float A512 = powc(512);
constexpr float A1024 = powc(1024);
constexpr float A2048 = powc(2048); // decay across one wave (64 chunks)
constexpr float A4096 = powc(4096);

__global__ __launch_bounds__(BLOCK) void ema_kernel(const float* __restrict__ x,
                                                    float* __restrict__ out) {
  __shared__ float4 sm4[UNITS];
  __shared__ float smW[NWAVE];

  const int tid = threadIdx.x;
  const long long base = (long long)blockIdx.x * (long long)T;

  // ---- stage in: coalesced b128 global loads -> swizzled b128 LDS writes ----
  const float4* xv = reinterpret_cast<const float4*>(x + base);
#pragma unroll
  for (int k = 0; k < VECS; ++k) {
    const int u = tid + BLOCK * k;
    sm4[swu(u)] = xv[u];
  }
  __syncthreads();

  // ---- per-thread sequential scan of its contiguous 32-elem chunk ----
  float4 acc[VECS];
  float run = 0.0f;
#pragma unroll
  for (int e = 0; e < VECS; ++e) {
    const float4 v = sm4[swu(tid * VECS + e)];
    run = fmaf(run, A1, M * v.x); acc[e].x = run;
    run = fmaf(run, A1, M * v.y); acc[e].y = run;
    run = fmaf(run, A1, M * v.z); acc[e].z = run;
    run = fmaf(run, A1, M * v.w); acc[e].w = run;
  }

  const int lane = tid & 63;
  const int w = tid >> 6;

  // ---- Kogge-Stone inclusive scan of chunk-finals across the wave ----
  float S = run;
  {
    float t;
    t = __shfl_up(S, 1, 64);  if (lane >= 1)  S = fmaf(t, A32,   S);
    t = __shfl_up(S, 2, 64);  if (lane >= 2)  S = fmaf(t, A64,   S);
    t = __shfl_up(S, 4, 64);  if (lane >= 4)  S = fmaf(t, A128,  S);
    t = __shfl_up(S, 8, 64);  if (lane >= 8)  S = fmaf(t, A256,  S);
    t = __shfl_up(S, 16, 64); if (lane >= 16) S = fmaf(t, A512,  S);
    t = __shfl_up(S, 32, 64); if (lane >= 32) S = fmaf(t, A1024, S);
  }
  if (lane == 63) smW[w] = S;  // wave total
  const float Sprev = __shfl_up(S, 1, 64);
  __syncthreads();

  // cross-wave prefix: Q_w = sum_{v<w} A2048^(w-1-v) * W_v
  float Q = 0.0f;
#pragma unroll
  for (int v = 0; v < NWAVE - 1; ++v) {
    if (v < w) Q = fmaf(Q, A2048, smW[v]);
  }

  // Dlane = A32^lane (binary decomposition)
  float Dlane = 1.0f;
  if (lane & 1)  Dlane *= A32;
  if (lane & 2)  Dlane *= A64;
  if (lane & 4)  Dlane *= A128;
  if (lane & 8)  Dlane *= A256;
  if (lane & 16) Dlane *= A512;
  if (lane & 32) Dlane *= A1024;

  // carry = y[chunk_base - 1]
  const float carry = (lane ? Sprev : 0.0f) + Dlane * Q;

  // Pt = 0.99^(32*tid) (binary decomposition)
  float Pt = 1.0f;
  if (tid & 1)   Pt *= A32;
  if (tid & 2)   Pt *= A64;
  if (tid & 4)   Pt *= A128;
  if (tid & 8)   Pt *= A256;
  if (tid & 16)  Pt *= A512;
  if (tid & 32)  Pt *= A1024;
  if (tid & 64)  Pt *= A2048;
  if (tid & 128) Pt *= A4096;

  // ---- epilogue: carry add + bias correction, b128 write back to LDS ----
#pragma unroll
  for (int e = 0; e < VECS; ++e) {
    const float p0 = PW.p[e * 4 + 1];
    const float p1 = PW.p[e * 4 + 2];
    const float p2 = PW.p[e * 4 + 3];
    const float p3 = PW.p[e * 4 + 4];
    float4 r;
    r.x = fmaf(carry, p0, acc[e].x) * __builtin_amdgcn_rcpf(1.0f - Pt * p0);
    r.y = fmaf(carry, p1, acc[e].y) * __builtin_amdgcn_rcpf(1.0f - Pt * p1);
    r.z = fmaf(carry, p2, acc[e].z) * __builtin_amdgcn_rcpf(1.0f - Pt * p2);
    r.w = fmaf(carry, p3, acc[e].w) * __builtin_amdgcn_rcpf(1.0f - Pt * p3);
    sm4[swu(tid * VECS + e)] = r;
  }
  __syncthreads();

  // ---- stage out: swizzled b128 LDS reads -> coalesced b128 global stores ----
  float4* ov = reinterpret_cast<float4*>(out + base);
#pragma unroll
  for (int k = 0; k < VECS; ++k) {
    const int u = tid + BLOCK * k;
    ov[u] = sm4[swu(u)];
  }
}

}  // namespace

extern "C" void kernel_launch(void* const* d_in, const int* in_sizes, int n_in,
                              void* d_out, int out_size, void* d_ws, size_t ws_size,
                              hipStream_t stream) {
  const float* x = (const float*)d_in[0];
  float* out = (float*)d_out;
  const int rows = in_sizes[0] / T;  // 32*256 = 8192
  ema_kernel<<<dim3(rows), dim3(BLOCK), 0, stream>>>(x, out);
}